// Round 10
// baseline (3893.758 us; speedup 1.0000x reference)
//
#include <hip/hip_runtime.h>
#include <math.h>

#define N_RES 2048
#define N_IN  128
#define T_SEQ 2048
#define NB    128      // blocks in recurrence kernel
#define ROWS  16       // rows per block
#define KR    4        // ring slots (power of 2; skew bound gives 2 slots slack)
#define RREP  4        // xring replicas (fan-in 128 -> 32 readers per line)

typedef unsigned long long u64;

// ---------------- Kernel 1: U = input @ W_in^T  -> d_out (row t = U[t]) ----
__global__ __launch_bounds__(256) void u_gemm(
    const float* __restrict__ in, const float* __restrict__ win,
    float* __restrict__ out)
{
  __shared__ float As[64][65];
  __shared__ float Bs[64][65];
  const int tid = threadIdx.x;
  const int t0 = blockIdx.y * 64;
  const int n0 = blockIdx.x * 64;
  const int tx = tid & 15, ty = tid >> 4;

  float acc[4][4];
  #pragma unroll
  for (int r = 0; r < 4; ++r)
    #pragma unroll
    for (int c = 0; c < 4; ++c) acc[r][c] = 0.f;

  for (int k0 = 0; k0 < N_IN; k0 += 64) {
    __syncthreads();
    #pragma unroll
    for (int i = 0; i < 4; ++i) {
      int idx = tid + i * 256;
      int row = idx >> 4;
      int k4  = (idx & 15) << 2;
      float4 a = *(const float4*)(in  + (size_t)(t0 + row) * N_IN + k0 + k4);
      As[row][k4+0] = a.x; As[row][k4+1] = a.y; As[row][k4+2] = a.z; As[row][k4+3] = a.w;
      float4 b = *(const float4*)(win + (size_t)(n0 + row) * N_IN + k0 + k4);
      Bs[row][k4+0] = b.x; Bs[row][k4+1] = b.y; Bs[row][k4+2] = b.z; Bs[row][k4+3] = b.w;
    }
    __syncthreads();
    for (int k = 0; k < 64; ++k) {
      float a[4], b[4];
      #pragma unroll
      for (int r = 0; r < 4; ++r) a[r] = As[ty*4+r][k];
      #pragma unroll
      for (int c = 0; c < 4; ++c) b[c] = Bs[tx*4+c][k];
      #pragma unroll
      for (int r = 0; r < 4; ++r)
        #pragma unroll
        for (int c = 0; c < 4; ++c) acc[r][c] += a[r] * b[c];
    }
  }
  #pragma unroll
  for (int r = 0; r < 4; ++r) {
    float4 v = make_float4(acc[r][0], acc[r][1], acc[r][2], acc[r][3]);
    *(float4*)(out + (size_t)(t0 + ty*4 + r) * N_RES + n0 + tx*4) = v;
  }
}

// ---- DPP helpers ----------------------------------------------------------
template<int CTRL>
__device__ __forceinline__ float xdpp(float v)
{
  return __uint_as_float(__builtin_amdgcn_update_dpp(
      0, (int)__float_as_uint(v), CTRL, 0xF, 0xF, true));
}
// quad_perm[1,0,3,2] (xor1) = 0xB1 ; quad_perm[2,3,0,1] (xor2) = 0x4E
// row_ror:8 = 0x128 : within 16-lane rows, (i+8)%16 == i^8

// ---- fold-and-keep wave reduction: 16 partials -> 1 full row sum per lane.
// Lane L ends with the complete sum of row rml(L) =
// (L&1)*8 + ((L>>1)&1)*4 + ((L>>2)&1)*2 + ((L>>3)&1)  (bijection on 0..15
// for lanes 0..15, duplicated x4 across the wave).
__device__ __forceinline__ float fold_reduce16(float v[16], int lane)
{
  #pragma unroll
  for (int r = 0; r < 8; ++r) {
    float send = (lane & 1) ? v[r] : v[r + 8];
    float recv = xdpp<0xB1>(send);
    v[r] = ((lane & 1) ? v[r + 8] : v[r]) + recv;
  }
  #pragma unroll
  for (int r = 0; r < 4; ++r) {
    float send = (lane & 2) ? v[r] : v[r + 4];
    float recv = xdpp<0x4E>(send);
    v[r] = ((lane & 2) ? v[r + 4] : v[r]) + recv;
  }
  #pragma unroll
  for (int r = 0; r < 2; ++r) {
    float send = (lane & 4) ? v[r] : v[r + 2];
    float recv = __shfl_xor(send, 4, 64);
    v[r] = ((lane & 4) ? v[r + 2] : v[r]) + recv;
  }
  {
    float send = (lane & 8) ? v[0] : v[1];
    float recv = xdpp<0x128>(send);          // xor8 within 16-lane row
    v[0] = ((lane & 8) ? v[1] : v[0]) + recv;
  }
  v[0] += __shfl_xor(v[0], 16, 64);
  v[0] += __shfl_xor(v[0], 32, 64);
  return v[0];
}

// ---------------- Kernel 2: recurrence, tagged-ring (LLC-resident) ---------
// 128 blocks x 256 threads. Block b owns rows [16b,16b+16); thread t owns
// cols {t+256j}. Communication: K=4-slot ring of 64-bit words, value =
// (t<<32)|fp32(x). Tag==t is the readiness test; tag+payload are one atomic
// word. Total surface = KR*RREP*N_RES*8B = 256 KB -> LLC-resident, polls at
// LLC latency, zero memset needed (0xAA poison tag never matches t<2048).
// Overwrite safety: block at step t implies all blocks >= t-1, laggard reads
// x_{t-2}; producer at t overwrites x_{t-4} -> 2 slots slack.
__global__ __launch_bounds__(256, 1) void esn_recur_v9(
    const float* __restrict__ wres, float* __restrict__ out,
    u64* __restrict__ xring)
{
  const int tid = threadIdx.x;
  const int lane = tid & 63;
  const int row0 = blockIdx.x * ROWS;
  const int wave = tid >> 6;
  const float inv = 0.022097086912079608f;   // 1/sqrt(2048)
  const int rml = (lane & 1) * 8 + ((lane >> 1) & 1) * 4
                + ((lane >> 2) & 1) * 2 + ((lane >> 3) & 1);
  const int rb = blockIdx.x & (RREP - 1);    // my replica

  // W: w[r][j] = W[row0+r][tid + 256*j]; coalesced, register-resident.
  float w[ROWS][8];
  #pragma unroll
  for (int r = 0; r < ROWS; ++r) {
    const float* p = wres + (size_t)(row0 + r) * N_RES + tid;
    #pragma unroll
    for (int j = 0; j < 8; ++j) w[r][j] = p[j * 256];
  }

  __shared__ float red[2][4][ROWS];   // [t&1][wave][row], waves 1..3 only

  // t = 0: x0 = erf(U[0]) * inv; publish (tag 0) to all replicas of slot 0
  if (tid < ROWS) {
    float x0 = erff(out[row0 + tid]) * inv;
    u64 val = (u64)__float_as_uint(x0);      // tag 0 in high word
    for (int rep = 0; rep < RREP; ++rep)
      __hip_atomic_store(xring + ((size_t)0 * RREP + rep) * N_RES + row0 + tid,
                         val, __ATOMIC_RELAXED, __HIP_MEMORY_SCOPE_AGENT);
    out[row0 + tid] = x0;
  }
  __syncthreads();

  for (int t = 1; t < T_SEQ; ++t) {
    const int p = t & 1;
    // own U[t] slot for row rml — issued before the poll, hides under it
    float u = out[(size_t)t * N_RES + row0 + rml];

    // ---- poll own 8 ring words of slot (t-1)&3 until tag == t-1 ----
    const u64* xr = xring + ((size_t)((t - 1) & (KR - 1)) * RREP + rb) * N_RES + tid;
    const unsigned int tagx = (unsigned int)(t - 1);
    u64 xb[8];
    unsigned int bad;
    do {
      #pragma unroll
      for (int j = 0; j < 8; ++j)
        xb[j] = __hip_atomic_load(xr + j * 256, __ATOMIC_RELAXED,
                                  __HIP_MEMORY_SCOPE_AGENT);
      bad  = ((unsigned int)(xb[0] >> 32) ^ tagx) | ((unsigned int)(xb[1] >> 32) ^ tagx);
      bad |= ((unsigned int)(xb[2] >> 32) ^ tagx) | ((unsigned int)(xb[3] >> 32) ^ tagx);
      bad |= ((unsigned int)(xb[4] >> 32) ^ tagx) | ((unsigned int)(xb[5] >> 32) ^ tagx);
      bad |= ((unsigned int)(xb[6] >> 32) ^ tagx) | ((unsigned int)(xb[7] >> 32) ^ tagx);
    } while (bad);

    // partial matvec: 16 rows x 8 cols (payload = low 32 bits)
    float x[8];
    #pragma unroll
    for (int j = 0; j < 8; ++j) x[j] = __uint_as_float((unsigned int)xb[j]);
    float acc[ROWS];
    #pragma unroll
    for (int r = 0; r < ROWS; ++r) {
      acc[r] = w[r][0]*x[0] + w[r][1]*x[1] + w[r][2]*x[2] + w[r][3]*x[3]
             + w[r][4]*x[4] + w[r][5]*x[5] + w[r][6]*x[6] + w[r][7]*x[7];
    }
    float s = fold_reduce16(acc, lane);   // lane holds full sum of row rml

    if (wave != 0 && lane < ROWS) red[p][wave][rml] = s;
    __syncthreads();

    // wave 0, lanes 0..15 finalize row rml (bijection; consistent with u)
    if (tid < ROWS) {
      float tot = s + red[p][1][rml] + red[p][2][rml] + red[p][3][rml];
      float xt = erff(u + tot) * inv;
      u64 val = ((u64)(unsigned int)t << 32) | (u64)__float_as_uint(xt);
      u64* dst = xring + (size_t)(t & (KR - 1)) * RREP * N_RES + row0 + rml;
      #pragma unroll
      for (int rep = 0; rep < RREP; ++rep)
        __hip_atomic_store(dst + (size_t)rep * N_RES, val,
                           __ATOMIC_RELAXED, __HIP_MEMORY_SCOPE_AGENT);
      out[(size_t)t * N_RES + row0 + rml] = xt;   // plain; after signals
    }
    // parity buffer + barrier ordering bounds skew <= 1 step: no 2nd barrier
  }
}

// ---------------- fallback (R2 flag barrier) if ws too small ---------------
#define FSTR 4
__global__ __launch_bounds__(256, 1) void esn_recur_flags(
    const float* __restrict__ wres, float* out, int* ws)
{
  const int b = blockIdx.x;
  const int tid = threadIdx.x;
  const int lane = tid & 63;
  const int wave = tid >> 6;
  const int row0 = b * ROWS;
  const float inv = 0.022097086912079608f;

  float w[ROWS][8];
  #pragma unroll
  for (int r = 0; r < ROWS; ++r) {
    const float* p = wres + (size_t)(row0 + r) * N_RES + tid;
    #pragma unroll
    for (int j = 0; j < 8; ++j) w[r][j] = p[j * 256];
  }

  __shared__ float red[ROWS][4];
  int* flags = ws;

  if (tid < ROWS) {
    float u = out[row0 + tid];
    __hip_atomic_store(out + row0 + tid, erff(u) * inv,
                       __ATOMIC_RELAXED, __HIP_MEMORY_SCOPE_AGENT);
  }
  if (wave == 0) {
    asm volatile("s_waitcnt vmcnt(0)" ::: "memory");
    if (lane == 0)
      __hip_atomic_store(flags + b * FSTR, 1, __ATOMIC_RELAXED, __HIP_MEMORY_SCOPE_AGENT);
  }

  for (int t = 1; t < T_SEQ; ++t) {
    if (wave == 0) {
      const int* f0 = flags + lane * FSTR;
      const int* f1 = flags + (lane + 64) * FSTR;
      bool ok;
      do {
        int a = __hip_atomic_load(f0, __ATOMIC_RELAXED, __HIP_MEMORY_SCOPE_AGENT);
        int c = __hip_atomic_load(f1, __ATOMIC_RELAXED, __HIP_MEMORY_SCOPE_AGENT);
        ok = (a >= t) && (c >= t);
      } while (!__all(ok));
    }
    __syncthreads();

    float u = 0.f;
    if (tid < ROWS) u = out[(size_t)t * N_RES + row0 + tid];

    const float* xrow = out + (size_t)(t - 1) * N_RES + tid;
    float x[8];
    #pragma unroll
    for (int j = 0; j < 8; ++j)
      x[j] = __hip_atomic_load(xrow + j * 256, __ATOMIC_RELAXED, __HIP_MEMORY_SCOPE_AGENT);

    float acc[ROWS];
    #pragma unroll
    for (int r = 0; r < ROWS; ++r) {
      acc[r] = w[r][0]*x[0] + w[r][1]*x[1] + w[r][2]*x[2] + w[r][3]*x[3]
             + w[r][4]*x[4] + w[r][5]*x[5] + w[r][6]*x[6] + w[r][7]*x[7];
    }
    #pragma unroll
    for (int m = 1; m < 64; m <<= 1) {
      #pragma unroll
      for (int r = 0; r < ROWS; ++r)
        acc[r] += __shfl_xor(acc[r], m, 64);
    }
    if (lane == 0) {
      #pragma unroll
      for (int r = 0; r < ROWS; ++r) red[r][wave] = acc[r];
    }
    __syncthreads();
    if (tid < ROWS) {
      float s = red[tid][0] + red[tid][1] + red[tid][2] + red[tid][3];
      __hip_atomic_store(out + (size_t)t * N_RES + row0 + tid, erff(u + s) * inv,
                         __ATOMIC_RELAXED, __HIP_MEMORY_SCOPE_AGENT);
    }
    if (wave == 0) {
      asm volatile("s_waitcnt vmcnt(0)" ::: "memory");
      if (lane == 0)
        __hip_atomic_store(flags + b * FSTR, t + 1,
                           __ATOMIC_RELAXED, __HIP_MEMORY_SCOPE_AGENT);
    }
  }
}

extern "C" void kernel_launch(void* const* d_in, const int* in_sizes, int n_in,
                              void* d_out, int out_size, void* d_ws, size_t ws_size,
                              hipStream_t stream)
{
  const float* input = (const float*)d_in[0];
  const float* w_in  = (const float*)d_in[1];
  const float* w_res = (const float*)d_in[2];
  float* out = (float*)d_out;

  const size_t ring_bytes = (size_t)KR * RREP * N_RES * sizeof(u64);  // 256 KiB

  dim3 g1(N_RES / 64, T_SEQ / 64), b1(256);
  hipLaunchKernelGGL(u_gemm, g1, b1, 0, stream, input, w_in, out);

  if (ws_size >= ring_bytes) {
    // no memset: 0xAA poison in d_ws gives tag 0xAAAAAAAA, never a valid t
    u64* xring = (u64*)d_ws;
    void* args[] = { (void*)&w_res, (void*)&out, (void*)&xring };
    hipLaunchCooperativeKernel((void*)esn_recur_v9, dim3(NB), dim3(256),
                               args, 0, stream);
  } else {
    int* ws = (int*)d_ws;
    size_t clr = ws_size < 4096 ? ws_size : 4096;
    hipMemsetAsync(d_ws, 0, clr, stream);
    void* args[] = { (void*)&w_res, (void*)&out, (void*)&ws };
    hipLaunchCooperativeKernel((void*)esn_recur_flags, dim3(NB), dim3(256),
                               args, 0, stream);
  }
}

// Round 11
// 3408.371 us; speedup vs baseline: 1.1424x; 1.1424x over previous
//
#include <hip/hip_runtime.h>
#include <math.h>

#define N_RES 2048
#define N_IN  128
#define T_SEQ 2048
#define NB    128      // blocks in recurrence kernel
#define ROWS  16       // rows per block
#define RREP  4        // x replicas == waves per block (wave w stores replica w)

typedef unsigned int u32x4 __attribute__((ext_vector_type(4)));

// ---------------- Kernel 1: U = input @ W_in^T  -> d_out (row t = U[t]) ----
__global__ __launch_bounds__(256) void u_gemm(
    const float* __restrict__ in, const float* __restrict__ win,
    float* __restrict__ out)
{
  __shared__ float As[64][65];
  __shared__ float Bs[64][65];
  const int tid = threadIdx.x;
  const int t0 = blockIdx.y * 64;
  const int n0 = blockIdx.x * 64;
  const int tx = tid & 15, ty = tid >> 4;

  float acc[4][4];
  #pragma unroll
  for (int r = 0; r < 4; ++r)
    #pragma unroll
    for (int c = 0; c < 4; ++c) acc[r][c] = 0.f;

  for (int k0 = 0; k0 < N_IN; k0 += 64) {
    __syncthreads();
    #pragma unroll
    for (int i = 0; i < 4; ++i) {
      int idx = tid + i * 256;
      int row = idx >> 4;
      int k4  = (idx & 15) << 2;
      float4 a = *(const float4*)(in  + (size_t)(t0 + row) * N_IN + k0 + k4);
      As[row][k4+0] = a.x; As[row][k4+1] = a.y; As[row][k4+2] = a.z; As[row][k4+3] = a.w;
      float4 b = *(const float4*)(win + (size_t)(n0 + row) * N_IN + k0 + k4);
      Bs[row][k4+0] = b.x; Bs[row][k4+1] = b.y; Bs[row][k4+2] = b.z; Bs[row][k4+3] = b.w;
    }
    __syncthreads();
    for (int k = 0; k < 64; ++k) {
      float a[4], b[4];
      #pragma unroll
      for (int r = 0; r < 4; ++r) a[r] = As[ty*4+r][k];
      #pragma unroll
      for (int c = 0; c < 4; ++c) b[c] = Bs[tx*4+c][k];
      #pragma unroll
      for (int r = 0; r < 4; ++r)
        #pragma unroll
        for (int c = 0; c < 4; ++c) acc[r][c] += a[r] * b[c];
    }
  }
  #pragma unroll
  for (int r = 0; r < 4; ++r) {
    float4 v = make_float4(acc[r][0], acc[r][1], acc[r][2], acc[r][3]);
    *(float4*)(out + (size_t)(t0 + ty*4 + r) * N_RES + n0 + tx*4) = v;
  }
}

// ---- DPP helpers ----------------------------------------------------------
template<int CTRL>
__device__ __forceinline__ float xdpp(float v)
{
  return __uint_as_float(__builtin_amdgcn_update_dpp(
      0, (int)__float_as_uint(v), CTRL, 0xF, 0xF, true));
}
// quad_perm[1,0,3,2] (xor1) = 0xB1 ; quad_perm[2,3,0,1] (xor2) = 0x4E
// row_ror:8 = 0x128 : within 16-lane rows, (i+8)%16 == i^8

// ---- fold-and-keep wave reduction: 16 partials -> 1 full row sum per lane.
// Lane L ends with the complete sum of row rml(L) =
// (L&1)*8 + ((L>>1)&1)*4 + ((L>>2)&1)*2 + ((L>>3)&1)  (bijection on 0..15
// for lanes 0..15, duplicated x4 across the wave).
__device__ __forceinline__ float fold_reduce16(float v[16], int lane)
{
  #pragma unroll
  for (int r = 0; r < 8; ++r) {
    float send = (lane & 1) ? v[r] : v[r + 8];
    float recv = xdpp<0xB1>(send);
    v[r] = ((lane & 1) ? v[r + 8] : v[r]) + recv;
  }
  #pragma unroll
  for (int r = 0; r < 4; ++r) {
    float send = (lane & 2) ? v[r] : v[r + 4];
    float recv = xdpp<0x4E>(send);
    v[r] = ((lane & 2) ? v[r + 4] : v[r]) + recv;
  }
  #pragma unroll
  for (int r = 0; r < 2; ++r) {
    float send = (lane & 4) ? v[r] : v[r + 2];
    float recv = __shfl_xor(send, 4, 64);
    v[r] = ((lane & 4) ? v[r + 2] : v[r]) + recv;
  }
  {
    float send = (lane & 8) ? v[0] : v[1];
    float recv = xdpp<0x128>(send);          // xor8 within 16-lane row
    v[0] = ((lane & 8) ? v[1] : v[0]) + recv;
  }
  v[0] += __shfl_xor(v[0], 16, 64);
  v[0] += __shfl_xor(v[0], 32, 64);
  return v[0];
}

// ---- coherent 32B poll load: 2 x dwordx4, L1/L2-bypassing (sc0 sc1) -------
__device__ __forceinline__ void coherent_load32(const unsigned int* p,
                                                u32x4& a, u32x4& b)
{
  asm volatile(
      "global_load_dwordx4 %0, %2, off sc0 sc1\n\t"
      "global_load_dwordx4 %1, %2, off offset:16 sc0 sc1\n\t"
      "s_waitcnt vmcnt(0)"
      : "=&v"(a), "=&v"(b)
      : "v"(p)
      : "memory");
}

// ---------------- Kernel 2: recurrence v10 ---------------------------------
// R7 skeleton: data-as-flag (sentinel 0x7F7F7F7F), fresh lines per step,
// R=4 replicas, one barrier/step, parity LDS combine. New:
// (1) thread t owns CONTIGUOUS cols [8t,8t+8) -> poll = 2 vector loads/round;
// (2) all 4 waves finalize: wave w stores replica w (parallel signals).
__global__ __launch_bounds__(256, 1) void esn_recur_v10(
    const float* __restrict__ wres, float* __restrict__ out,
    unsigned int* __restrict__ xbuf)
{
  const int tid = threadIdx.x;
  const int lane = tid & 63;
  const int wave = tid >> 6;
  const int row0 = blockIdx.x * ROWS;
  const float inv = 0.022097086912079608f;   // 1/sqrt(2048)
  const int rml = (lane & 1) * 8 + ((lane >> 1) & 1) * 4
                + ((lane >> 2) & 1) * 2 + ((lane >> 3) & 1);
  const int rb = blockIdx.x & (RREP - 1);    // replica this block polls

  // W: w[r][j] = W[row0+r][8*tid + j]  (contiguous per-thread chunk)
  float w[ROWS][8];
  #pragma unroll
  for (int r = 0; r < ROWS; ++r) {
    const float* p = wres + (size_t)(row0 + r) * N_RES + 8 * tid;
    float4 lo = *(const float4*)p;
    float4 hi = *(const float4*)(p + 4);
    w[r][0]=lo.x; w[r][1]=lo.y; w[r][2]=lo.z; w[r][3]=lo.w;
    w[r][4]=hi.x; w[r][5]=hi.y; w[r][6]=hi.z; w[r][7]=hi.w;
  }

  __shared__ float red[2][4][ROWS];   // [t&1][wave][row] — conflict-free

  // t = 0: x0 = erf(U[0]) * inv; publish to all replicas (off critical loop)
  if (tid < ROWS) {
    float x0 = erff(out[row0 + tid]) * inv;
    for (int rep = 0; rep < RREP; ++rep)
      __hip_atomic_store(xbuf + (size_t)rep * N_RES + row0 + tid,
                         __float_as_uint(x0),
                         __ATOMIC_RELAXED, __HIP_MEMORY_SCOPE_AGENT);
    out[row0 + tid] = x0;
  }
  __syncthreads();

  for (int t = 1; t < T_SEQ; ++t) {
    const int p = t & 1;
    // own U[t] word for row rml — issued before the poll, hides under it
    float u = out[(size_t)t * N_RES + row0 + rml];

    // ---- poll own 32B of x_{t-1} in my replica (bit-30 sentinel test) ----
    const unsigned int* xp =
        xbuf + ((size_t)(t - 1) * RREP + rb) * N_RES + 8 * tid;
    u32x4 A, B;
    unsigned int orv;
    do {
      coherent_load32(xp, A, B);
      orv  = (A.x | A.y) | (A.z | A.w);
      orv |= (B.x | B.y) | (B.z | B.w);
    } while (orv & 0x40000000u);

    float x[8];
    x[0]=__uint_as_float(A.x); x[1]=__uint_as_float(A.y);
    x[2]=__uint_as_float(A.z); x[3]=__uint_as_float(A.w);
    x[4]=__uint_as_float(B.x); x[5]=__uint_as_float(B.y);
    x[6]=__uint_as_float(B.z); x[7]=__uint_as_float(B.w);

    // partial matvec: 16 rows x 8 contiguous cols
    float acc[ROWS];
    #pragma unroll
    for (int r = 0; r < ROWS; ++r) {
      acc[r] = w[r][0]*x[0] + w[r][1]*x[1] + w[r][2]*x[2] + w[r][3]*x[3]
             + w[r][4]*x[4] + w[r][5]*x[5] + w[r][6]*x[6] + w[r][7]*x[7];
    }
    float s = fold_reduce16(acc, lane);   // lane holds full sum of row rml

    if (lane < ROWS) red[p][wave][rml] = s;
    __syncthreads();

    // every wave finalizes; wave w signals replica w (parallel signals)
    float tot = red[p][0][rml] + red[p][1][rml]
              + red[p][2][rml] + red[p][3][rml];
    float xt = erff(u + tot) * inv;
    if (lane < ROWS) {
      __hip_atomic_store(
          xbuf + ((size_t)t * RREP + wave) * N_RES + row0 + rml,
          __float_as_uint(xt), __ATOMIC_RELAXED, __HIP_MEMORY_SCOPE_AGENT);
      if (wave == 0)
        out[(size_t)t * N_RES + row0 + rml] = xt;   // plain; after signal
    }
    // parity buffer + barrier ordering bounds skew <= 1 step: no 2nd barrier
  }
}

// ---------------- fallback (R2 flag barrier) if ws too small ---------------
#define FSTR 4
__global__ __launch_bounds__(256, 1) void esn_recur_flags(
    const float* __restrict__ wres, float* out, int* ws)
{
  const int b = blockIdx.x;
  const int tid = threadIdx.x;
  const int lane = tid & 63;
  const int wave = tid >> 6;
  const int row0 = b * ROWS;
  const float inv = 0.022097086912079608f;

  float w[ROWS][8];
  #pragma unroll
  for (int r = 0; r < ROWS; ++r) {
    const float* p = wres + (size_t)(row0 + r) * N_RES + tid;
    #pragma unroll
    for (int j = 0; j < 8; ++j) w[r][j] = p[j * 256];
  }

  __shared__ float red[ROWS][4];
  int* flags = ws;

  if (tid < ROWS) {
    float u = out[row0 + tid];
    __hip_atomic_store(out + row0 + tid, erff(u) * inv,
                       __ATOMIC_RELAXED, __HIP_MEMORY_SCOPE_AGENT);
  }
  if (wave == 0) {
    asm volatile("s_waitcnt vmcnt(0)" ::: "memory");
    if (lane == 0)
      __hip_atomic_store(flags + b * FSTR, 1, __ATOMIC_RELAXED, __HIP_MEMORY_SCOPE_AGENT);
  }

  for (int t = 1; t < T_SEQ; ++t) {
    if (wave == 0) {
      const int* f0 = flags + lane * FSTR;
      const int* f1 = flags + (lane + 64) * FSTR;
      bool ok;
      do {
        int a = __hip_atomic_load(f0, __ATOMIC_RELAXED, __HIP_MEMORY_SCOPE_AGENT);
        int c = __hip_atomic_load(f1, __ATOMIC_RELAXED, __HIP_MEMORY_SCOPE_AGENT);
        ok = (a >= t) && (c >= t);
      } while (!__all(ok));
    }
    __syncthreads();

    float u = 0.f;
    if (tid < ROWS) u = out[(size_t)t * N_RES + row0 + tid];

    const float* xrow = out + (size_t)(t - 1) * N_RES + tid;
    float x[8];
    #pragma unroll
    for (int j = 0; j < 8; ++j)
      x[j] = __hip_atomic_load(xrow + j * 256, __ATOMIC_RELAXED, __HIP_MEMORY_SCOPE_AGENT);

    float acc[ROWS];
    #pragma unroll
    for (int r = 0; r < ROWS; ++r) {
      acc[r] = w[r][0]*x[0] + w[r][1]*x[1] + w[r][2]*x[2] + w[r][3]*x[3]
             + w[r][4]*x[4] + w[r][5]*x[5] + w[r][6]*x[6] + w[r][7]*x[7];
    }
    #pragma unroll
    for (int m = 1; m < 64; m <<= 1) {
      #pragma unroll
      for (int r = 0; r < ROWS; ++r)
        acc[r] += __shfl_xor(acc[r], m, 64);
    }
    if (lane == 0) {
      #pragma unroll
      for (int r = 0; r < ROWS; ++r) red[r][wave] = acc[r];
    }
    __syncthreads();
    if (tid < ROWS) {
      float s = red[tid][0] + red[tid][1] + red[tid][2] + red[tid][3];
      __hip_atomic_store(out + (size_t)t * N_RES + row0 + tid, erff(u + s) * inv,
                         __ATOMIC_RELAXED, __HIP_MEMORY_SCOPE_AGENT);
    }
    if (wave == 0) {
      asm volatile("s_waitcnt vmcnt(0)" ::: "memory");
      if (lane == 0)
        __hip_atomic_store(flags + b * FSTR, t + 1,
                           __ATOMIC_RELAXED, __HIP_MEMORY_SCOPE_AGENT);
    }
  }
}

extern "C" void kernel_launch(void* const* d_in, const int* in_sizes, int n_in,
                              void* d_out, int out_size, void* d_ws, size_t ws_size,
                              hipStream_t stream)
{
  const float* input = (const float*)d_in[0];
  const float* w_in  = (const float*)d_in[1];
  const float* w_res = (const float*)d_in[2];
  float* out = (float*)d_out;

  const size_t xbytes = (size_t)T_SEQ * N_RES * sizeof(float);  // 16 MiB

  dim3 g1(N_RES / 64, T_SEQ / 64), b1(256);
  hipLaunchKernelGGL(u_gemm, g1, b1, 0, stream, input, w_in, out);

  if (ws_size >= (size_t)RREP * xbytes) {
    unsigned int* xbuf = (unsigned int*)d_ws;
    hipMemsetAsync(d_ws, 0x7F, (size_t)RREP * xbytes, stream);  // sentinel-fill
    void* args[] = { (void*)&w_res, (void*)&out, (void*)&xbuf };
    hipLaunchCooperativeKernel((void*)esn_recur_v10, dim3(NB), dim3(256),
                               args, 0, stream);
  } else {
    int* ws = (int*)d_ws;
    size_t clr = ws_size < 4096 ? ws_size : 4096;
    hipMemsetAsync(d_ws, 0, clr, stream);
    void* args[] = { (void*)&w_res, (void*)&out, (void*)&ws };
    hipLaunchCooperativeKernel((void*)esn_recur_flags, dim3(NB), dim3(256),
                               args, 0, stream);
  }
}

// Round 13
// 3142.910 us; speedup vs baseline: 1.2389x; 1.0845x over previous
//
#include <hip/hip_runtime.h>
#include <math.h>

#define N_RES 2048
#define N_IN  128
#define T_SEQ 2048
#define NB    128      // blocks in recurrence kernel
#define ROWS  16       // rows per block
#define RREP  4        // x replicas (reader fan-in 128 -> 32 per line)
#define SENT  0x7F7F7F7Fu   // sentinel (3.39e38); bit30 set. |x|<=0.0222 -> bit30 clear

// ---------------- Kernel 1: U = input @ W_in^T  -> d_out (row t = U[t]) ----
__global__ __launch_bounds__(256) void u_gemm(
    const float* __restrict__ in, const float* __restrict__ win,
    float* __restrict__ out)
{
  __shared__ float As[64][65];
  __shared__ float Bs[64][65];
  const int tid = threadIdx.x;
  const int t0 = blockIdx.y * 64;
  const int n0 = blockIdx.x * 64;
  const int tx = tid & 15, ty = tid >> 4;

  float acc[4][4];
  #pragma unroll
  for (int r = 0; r < 4; ++r)
    #pragma unroll
    for (int c = 0; c < 4; ++c) acc[r][c] = 0.f;

  for (int k0 = 0; k0 < N_IN; k0 += 64) {
    __syncthreads();
    #pragma unroll
    for (int i = 0; i < 4; ++i) {
      int idx = tid + i * 256;
      int row = idx >> 4;
      int k4  = (idx & 15) << 2;
      float4 a = *(const float4*)(in  + (size_t)(t0 + row) * N_IN + k0 + k4);
      As[row][k4+0] = a.x; As[row][k4+1] = a.y; As[row][k4+2] = a.z; As[row][k4+3] = a.w;
      float4 b = *(const float4*)(win + (size_t)(n0 + row) * N_IN + k0 + k4);
      Bs[row][k4+0] = b.x; Bs[row][k4+1] = b.y; Bs[row][k4+2] = b.z; Bs[row][k4+3] = b.w;
    }
    __syncthreads();
    for (int k = 0; k < 64; ++k) {
      float a[4], b[4];
      #pragma unroll
      for (int r = 0; r < 4; ++r) a[r] = As[ty*4+r][k];
      #pragma unroll
      for (int c = 0; c < 4; ++c) b[c] = Bs[tx*4+c][k];
      #pragma unroll
      for (int r = 0; r < 4; ++r)
        #pragma unroll
        for (int c = 0; c < 4; ++c) acc[r][c] += a[r] * b[c];
    }
  }
  #pragma unroll
  for (int r = 0; r < 4; ++r) {
    float4 v = make_float4(acc[r][0], acc[r][1], acc[r][2], acc[r][3]);
    *(float4*)(out + (size_t)(t0 + ty*4 + r) * N_RES + n0 + tx*4) = v;
  }
}

// ---- DPP helpers ----------------------------------------------------------
template<int CTRL>
__device__ __forceinline__ float xdpp(float v)
{
  return __uint_as_float(__builtin_amdgcn_update_dpp(
      0, (int)__float_as_uint(v), CTRL, 0xF, 0xF, true));
}
// quad_perm[1,0,3,2] (xor1) = 0xB1 ; quad_perm[2,3,0,1] (xor2) = 0x4E
// row_ror:8 = 0x128 : within 16-lane rows, (i+8)%16 == i^8

// ---- fold-and-keep wave reduction: 16 partials -> 1 full row sum per lane.
// Lane L ends with the complete sum of row rml(L) =
// (L&1)*8 + ((L>>1)&1)*4 + ((L>>2)&1)*2 + ((L>>3)&1)  (bijection on 0..15
// for lanes 0..15, duplicated x4 across the wave).
__device__ __forceinline__ float fold_reduce16(float v[16], int lane)
{
  #pragma unroll
  for (int r = 0; r < 8; ++r) {
    float send = (lane & 1) ? v[r] : v[r + 8];
    float recv = xdpp<0xB1>(send);
    v[r] = ((lane & 1) ? v[r + 8] : v[r]) + recv;
  }
  #pragma unroll
  for (int r = 0; r < 4; ++r) {
    float send = (lane & 2) ? v[r] : v[r + 4];
    float recv = xdpp<0x4E>(send);
    v[r] = ((lane & 2) ? v[r + 4] : v[r]) + recv;
  }
  #pragma unroll
  for (int r = 0; r < 2; ++r) {
    float send = (lane & 4) ? v[r] : v[r + 2];
    float recv = __shfl_xor(send, 4, 64);
    v[r] = ((lane & 4) ? v[r + 2] : v[r]) + recv;
  }
  {
    float send = (lane & 8) ? v[0] : v[1];
    float recv = xdpp<0x128>(send);          // xor8 within 16-lane row
    v[0] = ((lane & 8) ? v[1] : v[0]) + recv;
  }
  v[0] += __shfl_xor(v[0], 16, 64);
  v[0] += __shfl_xor(v[0], 32, 64);
  return v[0];
}

// ---- branchless fast erf (A&S 7.1.26), abs err <= 1.5e-7 ------------------
// __expf -> v_exp_f32 sequence; exp underflow at large |a| gives exactly +-1.
__device__ __forceinline__ float fast_erf(float a)
{
  float ax = fabsf(a);
  float t  = 1.0f / fmaf(0.3275911f, ax, 1.0f);
  float p  = fmaf(1.061405429f, t, -1.453152027f);
  p = fmaf(p, t, 1.421413741f);
  p = fmaf(p, t, -0.284496736f);
  p = fmaf(p, t, 0.254829592f);
  p *= t;
  float e = __expf(-ax * ax);
  float r = fmaf(-p, e, 1.0f);
  return copysignf(r, a);
}

// ---------------- Kernel 2: recurrence v12 (= R7 + setprio + fast_erf) -----
// 128 blocks x 256 threads. Block b owns rows [16b,16b+16); thread t owns
// cols {t+256j}. Data-as-flag (sentinel), fresh lines per step, R=4 replicas,
// one barrier/step, parity LDS combine. s_setprio 3 on the post-detect
// critical path so the finalize pre-empts sibling polls in CU issue
// arbitration; polls run at prio 0.
__global__ __launch_bounds__(256, 1) void esn_recur_v12(
    const float* __restrict__ wres, float* __restrict__ out,
    unsigned int* __restrict__ xbuf)
{
  const int tid = threadIdx.x;
  const int lane = tid & 63;
  const int row0 = blockIdx.x * ROWS;
  const int wave = tid >> 6;
  const float inv = 0.022097086912079608f;   // 1/sqrt(2048)
  const int rml = (lane & 1) * 8 + ((lane >> 1) & 1) * 4
                + ((lane >> 2) & 1) * 2 + ((lane >> 3) & 1);
  const int rb = blockIdx.x & (RREP - 1);    // replica this block polls

  // W: w[r][j] = W[row0+r][tid + 256*j]; coalesced, register-resident.
  float w[ROWS][8];
  #pragma unroll
  for (int r = 0; r < ROWS; ++r) {
    const float* p = wres + (size_t)(row0 + r) * N_RES + tid;
    #pragma unroll
    for (int j = 0; j < 8; ++j) w[r][j] = p[j * 256];
  }

  __shared__ float red[2][4][ROWS];   // [t&1][wave][row] — conflict-free

  // t = 0: x0 = erf(U[0]) * inv; publish to all replicas
  if (tid < ROWS) {
    float x0 = fast_erf(out[row0 + tid]) * inv;
    for (int rep = 0; rep < RREP; ++rep)
      __hip_atomic_store(xbuf + (size_t)rep * N_RES + row0 + tid,
                         __float_as_uint(x0),
                         __ATOMIC_RELAXED, __HIP_MEMORY_SCOPE_AGENT);
    out[row0 + tid] = x0;
  }
  __syncthreads();

  for (int t = 1; t < T_SEQ; ++t) {
    const int p = t & 1;
    // own U[t] slot for row rml — issued before the poll, hides under it
    float u = out[(size_t)t * N_RES + row0 + rml];

    // ---- poll own 8 x words of row t-1 (bit-30 sentinel test), prio 0 ----
    const unsigned int* xr = xbuf + ((size_t)(t - 1) * RREP + rb) * N_RES + tid;
    unsigned int xb[8];
    unsigned int orv;
    do {
      #pragma unroll
      for (int j = 0; j < 8; ++j)
        xb[j] = __hip_atomic_load(xr + j * 256, __ATOMIC_RELAXED,
                                  __HIP_MEMORY_SCOPE_AGENT);
      orv  = (xb[0] | xb[1]) | (xb[2] | xb[3]);
      orv |= (xb[4] | xb[5]) | (xb[6] | xb[7]);
    } while (orv & 0x40000000u);

    asm volatile("s_setprio 3" ::: "memory");   // critical path begins

    // partial matvec: 16 rows x 8 cols
    float acc[ROWS];
    #pragma unroll
    for (int r = 0; r < ROWS; ++r) {
      acc[r] = w[r][0]*__uint_as_float(xb[0]) + w[r][1]*__uint_as_float(xb[1])
             + w[r][2]*__uint_as_float(xb[2]) + w[r][3]*__uint_as_float(xb[3])
             + w[r][4]*__uint_as_float(xb[4]) + w[r][5]*__uint_as_float(xb[5])
             + w[r][6]*__uint_as_float(xb[6]) + w[r][7]*__uint_as_float(xb[7]);
    }
    float s = fold_reduce16(acc, lane);   // lane holds full sum of row rml

    if (wave != 0 && lane < ROWS) red[p][wave][rml] = s;
    __syncthreads();

    // wave 0, lanes 0..15 finalize row rml (bijection; consistent with u)
    if (tid < ROWS) {
      float tot = s + red[p][1][rml] + red[p][2][rml] + red[p][3][rml];
      float xt = fast_erf(u + tot) * inv;
      unsigned int xu = __float_as_uint(xt);
      unsigned int* dst = xbuf + (size_t)t * RREP * N_RES + row0 + rml;
      #pragma unroll
      for (int rep = 0; rep < RREP; ++rep)
        __hip_atomic_store(dst + (size_t)rep * N_RES, xu,
                           __ATOMIC_RELAXED, __HIP_MEMORY_SCOPE_AGENT);
      out[(size_t)t * N_RES + row0 + rml] = xt;   // plain; after signals
    }
    asm volatile("s_setprio 0" ::: "memory");   // back to poll priority
    // parity buffer + barrier ordering bounds skew <= 1 step: no 2nd barrier
  }
}

// ---------------- fallback (R2 flag barrier) if ws too small ---------------
#define FSTR 4
__global__ __launch_bounds__(256, 1) void esn_recur_flags(
    const float* __restrict__ wres, float* out, int* ws)
{
  const int b = blockIdx.x;
  const int tid = threadIdx.x;
  const int lane = tid & 63;
  const int wave = tid >> 6;
  const int row0 = b * ROWS;
  const float inv = 0.022097086912079608f;

  float w[ROWS][8];
  #pragma unroll
  for (int r = 0; r < ROWS; ++r) {
    const float* p = wres + (size_t)(row0 + r) * N_RES + tid;
    #pragma unroll
    for (int j = 0; j < 8; ++j) w[r][j] = p[j * 256];
  }

  __shared__ float red[ROWS][4];
  int* flags = ws;

  if (tid < ROWS) {
    float u = out[row0 + tid];
    __hip_atomic_store(out + row0 + tid, erff(u) * inv,
                       __ATOMIC_RELAXED, __HIP_MEMORY_SCOPE_AGENT);
  }
  if (wave == 0) {
    asm volatile("s_waitcnt vmcnt(0)" ::: "memory");
    if (lane == 0)
      __hip_atomic_store(flags + b * FSTR, 1, __ATOMIC_RELAXED, __HIP_MEMORY_SCOPE_AGENT);
  }

  for (int t = 1; t < T_SEQ; ++t) {
    if (wave == 0) {
      const int* f0 = flags + lane * FSTR;
      const int* f1 = flags + (lane + 64) * FSTR;
      bool ok;
      do {
        int a = __hip_atomic_load(f0, __ATOMIC_RELAXED, __HIP_MEMORY_SCOPE_AGENT);
        int c = __hip_atomic_load(f1, __ATOMIC_RELAXED, __HIP_MEMORY_SCOPE_AGENT);
        ok = (a >= t) && (c >= t);
      } while (!__all(ok));
    }
    __syncthreads();

    float u = 0.f;
    if (tid < ROWS) u = out[(size_t)t * N_RES + row0 + tid];

    const float* xrow = out + (size_t)(t - 1) * N_RES + tid;
    float x[8];
    #pragma unroll
    for (int j = 0; j < 8; ++j)
      x[j] = __hip_atomic_load(xrow + j * 256, __ATOMIC_RELAXED, __HIP_MEMORY_SCOPE_AGENT);

    float acc[ROWS];
    #pragma unroll
    for (int r = 0; r < ROWS; ++r) {
      acc[r] = w[r][0]*x[0] + w[r][1]*x[1] + w[r][2]*x[2] + w[r][3]*x[3]
             + w[r][4]*x[4] + w[r][5]*x[5] + w[r][6]*x[6] + w[r][7]*x[7];
    }
    #pragma unroll
    for (int m = 1; m < 64; m <<= 1) {
      #pragma unroll
      for (int r = 0; r < ROWS; ++r)
        acc[r] += __shfl_xor(acc[r], m, 64);
    }
    if (lane == 0) {
      #pragma unroll
      for (int r = 0; r < ROWS; ++r) red[r][wave] = acc[r];
    }
    __syncthreads();
    if (tid < ROWS) {
      float s = red[tid][0] + red[tid][1] + red[tid][2] + red[tid][3];
      __hip_atomic_store(out + (size_t)t * N_RES + row0 + tid, erff(u + s) * inv,
                         __ATOMIC_RELAXED, __HIP_MEMORY_SCOPE_AGENT);
    }
    if (wave == 0) {
      asm volatile("s_waitcnt vmcnt(0)" ::: "memory");
      if (lane == 0)
        __hip_atomic_store(flags + b * FSTR, t + 1,
                           __ATOMIC_RELAXED, __HIP_MEMORY_SCOPE_AGENT);
    }
  }
}

extern "C" void kernel_launch(void* const* d_in, const int* in_sizes, int n_in,
                              void* d_out, int out_size, void* d_ws, size_t ws_size,
                              hipStream_t stream)
{
  const float* input = (const float*)d_in[0];
  const float* w_in  = (const float*)d_in[1];
  const float* w_res = (const float*)d_in[2];
  float* out = (float*)d_out;

  const size_t xbytes = (size_t)T_SEQ * N_RES * sizeof(float);  // 16 MiB

  dim3 g1(N_RES / 64, T_SEQ / 64), b1(256);
  hipLaunchKernelGGL(u_gemm, g1, b1, 0, stream, input, w_in, out);

  if (ws_size >= (size_t)RREP * xbytes) {
    unsigned int* xbuf = (unsigned int*)d_ws;
    (void)hipMemsetAsync(d_ws, 0x7F, (size_t)RREP * xbytes, stream);  // sentinel
    void* args[] = { (void*)&w_res, (void*)&out, (void*)&xbuf };
    (void)hipLaunchCooperativeKernel((void*)esn_recur_v12, dim3(NB), dim3(256),
                                     args, 0, stream);
  } else {
    int* ws = (int*)d_ws;
    size_t clr = ws_size < 4096 ? ws_size : 4096;
    (void)hipMemsetAsync(d_ws, 0, clr, stream);
    void* args[] = { (void*)&w_res, (void*)&out, (void*)&ws };
    (void)hipLaunchCooperativeKernel((void*)esn_recur_flags, dim3(NB), dim3(256),
                                     args, 0, stream);
  }
}